// Round 6
// baseline (291.026 us; speedup 1.0000x reference)
//
#include <hip/hip_runtime.h>

#define LDIM 4096
#define DDIM 64
#define KCODES 1024
#define BDIM 16
#define NROWS 65536   // BDIM * LDIM
#define NSLICE 8
#define SLICE_ROWS (NROWS / NSLICE)   // 8192
#define NGROUP 8                      // code groups of 128

typedef __attribute__((ext_vector_type(8))) short short8;
typedef __attribute__((ext_vector_type(16))) float float16v;

__device__ __forceinline__ unsigned int orderf(float f) {
  unsigned int u = __float_as_uint(f);
  return (u & 0x80000000u) ? ~u : (u | 0x80000000u);
}

__device__ __forceinline__ unsigned long long shfl_xor_u64(unsigned long long v, int m) {
  int lo = __shfl_xor((int)(unsigned int)(v & 0xffffffffull), m, 64);
  int hi = __shfl_xor((int)(unsigned int)(v >> 32), m, 64);
  return ((unsigned long long)(unsigned int)hi << 32) | (unsigned int)lo;
}

// bf16 RNE high part (as ushort bits)
__device__ __forceinline__ unsigned int bf16_rne(float x) {
  unsigned int u = __float_as_uint(x);
  return (u + 0x7FFFu + ((u >> 16) & 1u)) >> 16;
}

// async global->LDS, 16 B per lane; lds dest = wave-uniform base + lane*16
__device__ __forceinline__ void gl_lds16(const void* g, void* l) {
  __builtin_amdgcn_global_load_lds(
      (const __attribute__((address_space(1))) void*)g,
      (__attribute__((address_space(3))) void*)l, 16, 0, 0);
}

// ---------------------------------------------------------------------------
// prep: per-code norm + softmax table + PRE-SWIZZLED bf16 hi/lo codebook.
// Epk short index for code k, dim d: k*128 + ((t ^ (k&15))<<3) + (d&7),
// t = d>>3 (hi) or 8+(d>>3) (lo). Linear copy of any 128-code group lands
// the XOR-swizzled LDS image argmin wants.
// ---------------------------------------------------------------------------
__global__ void prep_kernel(const float* __restrict__ Ew,
                            float* __restrict__ enorm,
                            float* __restrict__ SE,
                            unsigned short* __restrict__ Epk) {
  int k = blockIdx.x;
  int d = threadIdx.x;
  float v = Ew[k * DDIM + d];
  float n2 = v * v;
  #pragma unroll
  for (int o = 32; o > 0; o >>= 1) n2 += __shfl_xor(n2, o, 64);
  float m = v;
  #pragma unroll
  for (int o = 32; o > 0; o >>= 1) m = fmaxf(m, __shfl_xor(m, o, 64));
  float e = expf(v - m);
  float Z = e;
  #pragma unroll
  for (int o = 32; o > 0; o >>= 1) Z += __shfl_xor(Z, o, 64);
  SE[k * DDIM + d] = e / Z;
  if (d == 0) enorm[k] = n2;

  unsigned int rh = bf16_rne(v);
  float hif = __uint_as_float(rh << 16);
  unsigned int rl = bf16_rne(v - hif);
  unsigned int base = (unsigned int)k * 128;
  int th = d >> 3, e8 = d & 7, x15 = k & 15;
  Epk[base + ((th ^ x15) << 3) + e8]       = (unsigned short)rh;
  Epk[base + (((8 + th) ^ x15) << 3) + e8] = (unsigned short)rl;
}

// ---------------------------------------------------------------------------
// argmin, codebook-resident split-K form. Block = (row-tile of 128) x
// (code group of 128). Stage cb group (32 KB DMA) + x tile (32 KB), ONE
// barrier, then pure LDS/MFMA/VALU — no barriers, no DMA deps in the loop.
// Per-row best merged globally via atomicMin on u64 (orderf(score)<<32|idx);
// ties -> smaller idx, matching the reference. 16 blocks/CU queued hide
// the per-block staging latency.
// ---------------------------------------------------------------------------
__launch_bounds__(256, 2)
__global__ void argmin_kernel(const float* __restrict__ inp,
                              const unsigned short* __restrict__ Epk,
                              const float* __restrict__ enorm,
                              unsigned long long* __restrict__ keymin) {
  __shared__ unsigned short lbuf[32768];   // 64 KB: [0,16K)=cb, [16K,32K)=xs
  __shared__ float ens[128];

  const int tid = threadIdx.x;
  const int lane = tid & 63;
  const int w = tid >> 6;
  const int half = lane >> 5;
  const int blk = blockIdx.x;
  const int grp = blk & 7;           // code group (adjacent blocks share x tile)
  const int rt = blk >> 3;           // row tile 0..511
  const int b = rt >> 5;
  const int l0 = (rt & 31) << 7;
  const float* xbase = inp + (size_t)b * DDIM * LDIM + l0;

  // ---- DMA codebook group (32 KB linear, pre-swizzled) -----------------
  {
    const char* src = (const char*)Epk + grp * 32768 + w * 8192;
    char* dst = (char*)lbuf + w * 8192;
    #pragma unroll
    for (int q = 0; q < 8; q++)
      gl_lds16(src + q * 1024 + (lane << 4), dst + q * 1024);
  }

  // ---- stage x tile as swizzled bf16 hi/lo into [16K,32K) shorts -------
  for (int i = tid; i < 8192; i += 256) {
    int d = i >> 7, l = i & 127;
    float x = xbase[(size_t)d * LDIM + l];
    unsigned int rh = bf16_rne(x);
    float hif = __uint_as_float(rh << 16);
    unsigned int rl = bf16_rne(x - hif);
    int th = d >> 3;
    int tl = 8 + th;
    lbuf[16384 + l * 128 + ((th ^ (l & 15)) << 3) + (d & 7)] = (unsigned short)rh;
    lbuf[16384 + l * 128 + ((tl ^ (l & 15)) << 3) + (d & 7)] = (unsigned short)rl;
  }
  if (tid < 32) {
    float4 v = ((const float4*)(enorm + grp * 128))[tid];
    *(float4*)&ens[tid << 2] = v;
  }
  __syncthreads();   // drains DMA + x stores; the ONLY barrier

  // ---- A-frags to registers: rows 32w..32w+31 --------------------------
  short8 afr[8];   // 0..3 = hi K-frags, 4..7 = lo K-frags
  {
    int row = w * 32 + (lane & 31);
    const unsigned short* xr = &lbuf[16384 + row * 128];
    #pragma unroll
    for (int s = 0; s < 4; s++) {
      afr[s]     = *(const short8*)&xr[(((2 * s + half) ^ (row & 15)) << 3)];
      afr[4 + s] = *(const short8*)&xr[(((8 + 2 * s + half) ^ (row & 15)) << 3)];
    }
  }

  float bsc[16];
  int bix[16];
  #pragma unroll
  for (int j = 0; j < 16; j++) { bsc[j] = 1e30f; bix[j] = 0; }

  #pragma unroll
  for (int tile = 0; tile < 4; tile++) {
    int crow = tile * 32 + (lane & 31);
    int ci = grp * 128 + crow;
    float en = ens[crow];

    const unsigned short* cr = &lbuf[crow * 128];
    short8 bfr[8];
    #pragma unroll
    for (int s = 0; s < 4; s++) {
      bfr[s]     = *(const short8*)&cr[(((2 * s + half) ^ (crow & 15)) << 3)];
      bfr[4 + s] = *(const short8*)&cr[(((8 + 2 * s + half) ^ (crow & 15)) << 3)];
    }

    float16v acc = {};
    #pragma unroll
    for (int s = 0; s < 4; s++)
      acc = __builtin_amdgcn_mfma_f32_32x32x16_bf16(afr[s], bfr[s], acc, 0, 0, 0);
    #pragma unroll
    for (int s = 0; s < 4; s++)
      acc = __builtin_amdgcn_mfma_f32_32x32x16_bf16(afr[s], bfr[4 + s], acc, 0, 0, 0);
    #pragma unroll
    for (int s = 0; s < 4; s++)
      acc = __builtin_amdgcn_mfma_f32_32x32x16_bf16(afr[4 + s], bfr[s], acc, 0, 0, 0);

    #pragma unroll
    for (int j = 0; j < 16; j++) {
      float sc = fmaf(-2.f, acc[j], en);
      if (sc < bsc[j]) { bsc[j] = sc; bix[j] = ci; }  // ascending ci: ties -> smaller
    }
  }

  // per-row reduce over the 32 cols, then one atomicMin per (row, group)
  #pragma unroll
  for (int j = 0; j < 16; j++) {
    unsigned long long key =
        ((unsigned long long)orderf(bsc[j]) << 32) | (unsigned int)bix[j];
    #pragma unroll
    for (int m = 1; m < 32; m <<= 1) {
      unsigned long long o = shfl_xor_u64(key, m);
      if (o < key) key = o;
    }
    if ((lane & 31) == 0) {
      int row_local = (j & 3) + 8 * (j >> 2) + 4 * half;
      int grow = rt * 128 + w * 32 + row_local;
      atomicMin(&keymin[grow], key);
    }
  }
}

// ---------------------------------------------------------------------------
// combine: key -> idx (+ counts histogram). 65536 threads.
// ---------------------------------------------------------------------------
__launch_bounds__(256)
__global__ void combine_kernel(const unsigned long long* __restrict__ keymin,
                               int* __restrict__ idx_ws,
                               float* __restrict__ outidx,
                               float* __restrict__ counts) {
  int row = blockIdx.x * 256 + threadIdx.x;
  int ci = (int)(keymin[row] & 0xffffffffull);
  idx_ws[row] = ci;
  outidx[row] = (float)ci;
  atomicAdd(&counts[ci], 1.0f);
}

// ---------------------------------------------------------------------------
// out + KL: quantized output write + KL partial sums.
// ---------------------------------------------------------------------------
__launch_bounds__(256)
__global__ void out_kl_kernel(const float* __restrict__ inp,
                              const float* __restrict__ Ew,
                              const float* __restrict__ SE,
                              const int* __restrict__ idx_ws,
                              float* __restrict__ out,
                              float* __restrict__ klacc) {
  int row = blockIdx.x * 256 + threadIdx.x;
  int b = row >> 12, l = row & 4095;
  const float* xp = inp + (size_t)b * DDIM * LDIM + l;
  float* op = out + (size_t)b * DDIM * LDIM + l;
  int k = idx_ws[row];
  const float* Ek = Ew + k * DDIM;
  const float* Qk = SE + k * DDIM;

  float Z = 0.f, S1 = 0.f, U = 0.f;
  #pragma unroll
  for (int d = 0; d < 64; d++) {
    float x = xp[d * LDIM];
    float e = expf(x);
    Z += e;
    S1 += e * x;
    U += e * Qk[d];
    op[d * LDIM] = Ek[d];
  }

  float kl = (S1 - U) / Z - logf(Z);
  #pragma unroll
  for (int o = 32; o > 0; o >>= 1) kl += __shfl_xor(kl, o, 64);
  if ((threadIdx.x & 63) == 0) atomicAdd(klacc, kl);
}

// ---------------------------------------------------------------------------
// csp + perplexity. 1 block x 1024.
// ---------------------------------------------------------------------------
__global__ void csp_kernel(const float* __restrict__ ema_cs,
                           const float* __restrict__ counts,
                           float* __restrict__ csp,
                           float* __restrict__ perp_out) {
  __shared__ float red1[16], red2[16];
  int k = threadIdx.x;
  float c = counts[k];
  float cs = ema_cs[k] * 0.9f + 0.1f * c;
  float n = cs;
  #pragma unroll
  for (int o = 32; o > 0; o >>= 1) n += __shfl_xor(n, o, 64);
  if ((k & 63) == 0) red1[k >> 6] = n;
  float a = c * (1.0f / 65536.0f);
  float ent = a * logf(a + 1e-10f);
  float es = ent;
  #pragma unroll
  for (int o = 32; o > 0; o >>= 1) es += __shfl_xor(es, o, 64);
  if ((k & 63) == 0) red2[k >> 6] = es;
  __syncthreads();
  if (k == 0) {
    float t1 = 0.f, t2 = 0.f;
    for (int i = 0; i < 16; i++) { t1 += red1[i]; t2 += red2[i]; }
    red1[0] = t1;
    *perp_out = expf(-t2);
  }
  __syncthreads();
  float N = red1[0];
  csp[k] = (cs + 1e-5f) / (N + 1024.0f * 1e-5f) * N;
}

// ---------------------------------------------------------------------------
// dw partial: dimension-sliced histogram. Zero global atomics.
// ---------------------------------------------------------------------------
__launch_bounds__(256)
__global__ void dw_partial_kernel(const float* __restrict__ inp,
                                  const int* __restrict__ idx_ws,
                                  float* __restrict__ partial) {
  __shared__ float dwp[KCODES];
  const int d = blockIdx.x & 63;
  const int slice = blockIdx.x >> 6;
  const int tid = threadIdx.x;

  #pragma unroll
  for (int i = 0; i < KCODES / 256; i++) dwp[tid + i * 256] = 0.f;
  __syncthreads();

  const int r0 = slice * SLICE_ROWS;
  for (int i = tid; i < SLICE_ROWS; i += 256) {
    int r = r0 + i;
    int b = r >> 12, l = r & 4095;
    float x = inp[(size_t)b * DDIM * LDIM + (size_t)d * LDIM + l];
    int k = idx_ws[r];
    atomicAdd(&dwp[k], x);
  }
  __syncthreads();

  float* dst = partial + ((size_t)slice * 64 + d) * KCODES;
  #pragma unroll
  for (int i = 0; i < KCODES / 256; i++) dst[tid + i * 256] = dwp[tid + i * 256];
}

// ---------------------------------------------------------------------------
// reduce partials + embed epilogue + loss scalar.
// ---------------------------------------------------------------------------
__launch_bounds__(256)
__global__ void reduce_embed_kernel(const float* __restrict__ partial,
                                    const float* __restrict__ emaw,
                                    const float* __restrict__ csp,
                                    const float* __restrict__ klacc,
                                    float* __restrict__ emb_out,
                                    float* __restrict__ loss_out) {
  int i = blockIdx.x * 256 + threadIdx.x;
  int k = i >> 6, d = i & 63;
  float s = 0.f;
  #pragma unroll
  for (int sl = 0; sl < NSLICE; sl++)
    s += partial[((size_t)sl * 64 + d) * KCODES + k];
  float v = fmaf(0.1f, s, emaw[i] * 0.9f);
  emb_out[i] = v / csp[k];
  if (i == 0) *loss_out = 0.1f * (*klacc) * (1.0f / 16.0f);
}

extern "C" void kernel_launch(void* const* d_in, const int* in_sizes, int n_in,
                              void* d_out, int out_size, void* d_ws, size_t ws_size,
                              hipStream_t stream) {
  const float* inp   = (const float*)d_in[0];   // (16,64,4096)
  const float* Ew    = (const float*)d_in[1];   // (1024,64)
  const float* emacs = (const float*)d_in[2];   // (1024,)
  const float* emaw  = (const float*)d_in[3];   // (1024,64)

  float* out      = (float*)d_out;              // (16,64,4096) = 4194304
  float* loss_out = out + 4194304;
  float* perp_out = out + 4194305;
  float* emb_out  = out + 4194306;              // 65536
  float* idxf_out = out + 4194306 + 65536;      // 65536 (indices as float)

  char* ws = (char*)d_ws;
  int*   idx_ws  = (int*)(ws);                  // 262144 B
  float* counts  = (float*)(ws + 262144);       // 4096 B  (zeroed)
  float* klacc   = (float*)(ws + 266240);       // 256 B   (zeroed)
  float* enorm   = (float*)(ws + 266496);       // 4096 B
  float* csp     = (float*)(ws + 270592);       // 4096 B
  float* SE      = (float*)(ws + 274688);       // 262144 B -> ends 536832
  unsigned short* Epk = (unsigned short*)(ws + 536832);          // 262144 B
  unsigned long long* keymin = (unsigned long long*)(ws + 798976); // 524288 B
  // dw partials alias Epk+keymin (both dead once combine_kernel finishes)
  float* partial = (float*)(ws + 536832);       // 2097152 B -> ends 2633984

  hipMemsetAsync(ws + 262144, 0, 4096 + 256, stream);
  hipMemsetAsync(ws + 798976, 0xFF, 524288, stream);

  prep_kernel<<<KCODES, 64, 0, stream>>>(Ew, enorm, SE, Epk);
  argmin_kernel<<<512 * NGROUP, 256, 0, stream>>>(inp, Epk, enorm, keymin);
  combine_kernel<<<NROWS / 256, 256, 0, stream>>>(keymin, idx_ws, idxf_out, counts);
  csp_kernel<<<1, 1024, 0, stream>>>(emacs, counts, csp, perp_out);
  dw_partial_kernel<<<64 * NSLICE, 256, 0, stream>>>(inp, idx_ws, partial);
  out_kl_kernel<<<NROWS / 256, 256, 0, stream>>>(inp, Ew, SE, idx_ws, out, klacc);
  reduce_embed_kernel<<<NROWS / 256, 256, 0, stream>>>(partial, emaw, csp, klacc,
                                                       emb_out, loss_out);
}

// Round 7
// 215.106 us; speedup vs baseline: 1.3529x; 1.3529x over previous
//
#include <hip/hip_runtime.h>

#define LDIM 4096
#define DDIM 64
#define KCODES 1024
#define BDIM 16
#define NROWS 65536   // BDIM * LDIM
#define NSLICE 8
#define SLICE_ROWS (NROWS / NSLICE)   // 8192

typedef __attribute__((ext_vector_type(8))) short short8;
typedef __attribute__((ext_vector_type(16))) float float16v;

__device__ __forceinline__ unsigned int orderf(float f) {
  unsigned int u = __float_as_uint(f);
  return (u & 0x80000000u) ? ~u : (u | 0x80000000u);
}

__device__ __forceinline__ unsigned long long shfl_xor_u64(unsigned long long v, int m) {
  int lo = __shfl_xor((int)(unsigned int)(v & 0xffffffffull), m, 64);
  int hi = __shfl_xor((int)(unsigned int)(v >> 32), m, 64);
  return ((unsigned long long)(unsigned int)hi << 32) | (unsigned int)lo;
}

// bf16 RNE high part (as ushort bits)
__device__ __forceinline__ unsigned int bf16_rne(float x) {
  unsigned int u = __float_as_uint(x);
  return (u + 0x7FFFu + ((u >> 16) & 1u)) >> 16;
}

// ---------------------------------------------------------------------------
// prep: per-code norm + softmax table + fragment-linear bf16 hi/lo codebook.
// Epk[k*128 + d] = hi(E[k][d]); Epk[k*128 + 64 + d] = lo. A 16 B run at
// (k*128 + 16s + 8h) is exactly one B-fragment register quad.
// ---------------------------------------------------------------------------
__global__ void prep_kernel(const float* __restrict__ Ew,
                            float* __restrict__ enorm,
                            float* __restrict__ SE,
                            unsigned short* __restrict__ Epk) {
  int k = blockIdx.x;
  int d = threadIdx.x;
  float v = Ew[k * DDIM + d];
  float n2 = v * v;
  #pragma unroll
  for (int o = 32; o > 0; o >>= 1) n2 += __shfl_xor(n2, o, 64);
  float m = v;
  #pragma unroll
  for (int o = 32; o > 0; o >>= 1) m = fmaxf(m, __shfl_xor(m, o, 64));
  float e = expf(v - m);
  float Z = e;
  #pragma unroll
  for (int o = 32; o > 0; o >>= 1) Z += __shfl_xor(Z, o, 64);
  SE[k * DDIM + d] = e / Z;
  if (d == 0) enorm[k] = n2;

  unsigned int rh = bf16_rne(v);
  float hif = __uint_as_float(rh << 16);
  unsigned int rl = bf16_rne(v - hif);
  Epk[k * 128 + d] = (unsigned short)rh;
  Epk[k * 128 + 64 + d] = (unsigned short)rl;
}

// ---------------------------------------------------------------------------
// argmin: LDS-free, barrier-free, atomic-free. One wave owns 32 rows:
// A-frags (x hi/lo) from coalesced global loads into registers; codebook
// streamed from L2 with register double-buffering (512 MB total ~ 14 us at
// L2 BW); 3 independent MFMA accumulator chains; per-row best reduced by a
// 5-step u64 butterfly and written directly. score = ||E||^2 - 2 x.E.
// ---------------------------------------------------------------------------
__launch_bounds__(256, 2)
__global__ void argmin_kernel(const float* __restrict__ inp,
                              const unsigned short* __restrict__ Epk,
                              const float* __restrict__ enorm,
                              int* __restrict__ idx_ws,
                              float* __restrict__ outidx) {
  const int tid = threadIdx.x;
  const int lane = tid & 63;
  const int w = tid >> 6;
  const int half = lane >> 5;
  const int m = lane & 31;
  const int row_base = blockIdx.x * 128 + w * 32;
  const int b = row_base >> 12;
  const int l0 = row_base & 4095;
  const float* xp = inp + (size_t)b * DDIM * LDIM + l0 + m;

  // ---- A-frags from global: lane holds x[row=m][d=16s+8*half+j] --------
  short8 afr[8];   // 0..3 = hi frags, 4..7 = lo frags
  #pragma unroll
  for (int s = 0; s < 4; s++) {
    #pragma unroll
    for (int j = 0; j < 8; j++) {
      int d = 16 * s + 8 * half + j;
      float x = xp[(size_t)d * LDIM];
      unsigned int rh = bf16_rne(x);
      float hif = __uint_as_float(rh << 16);
      unsigned int rl = bf16_rne(x - hif);
      afr[s][j] = (short)(unsigned short)rh;
      afr[4 + s][j] = (short)(unsigned short)rl;
    }
  }

  float bsc[16];
  int bix[16];
  #pragma unroll
  for (int j = 0; j < 16; j++) { bsc[j] = 1e30f; bix[j] = 0; }

  // B-frag base for this lane: code c = t*32 + m, 16 B run at 16s + 8h (+64 lo)
  const unsigned short* eb = Epk + m * 128 + half * 8;

  short8 bA[8], bB[8];
  float enA, enB;

  // load tile 0
  #pragma unroll
  for (int s = 0; s < 4; s++) {
    bA[s]     = *(const short8*)(eb + 16 * s);
    bA[4 + s] = *(const short8*)(eb + 64 + 16 * s);
  }
  enA = enorm[m];

  #pragma unroll 1
  for (int i = 0; i < 16; i++) {
    const int tB = 2 * i + 1;
    // prefetch tile tB
    {
      const unsigned short* p = eb + tB * 4096;
      #pragma unroll
      for (int s = 0; s < 4; s++) {
        bB[s]     = *(const short8*)(p + 16 * s);
        bB[4 + s] = *(const short8*)(p + 64 + 16 * s);
      }
      enB = enorm[tB * 32 + m];
    }
    // compute tile 2i from bA
    {
      float16v a0 = {}, a1 = {}, a2 = {};
      #pragma unroll
      for (int s = 0; s < 4; s++) {
        a0 = __builtin_amdgcn_mfma_f32_32x32x16_bf16(afr[s], bA[s], a0, 0, 0, 0);
        a1 = __builtin_amdgcn_mfma_f32_32x32x16_bf16(afr[s], bA[4 + s], a1, 0, 0, 0);
        a2 = __builtin_amdgcn_mfma_f32_32x32x16_bf16(afr[4 + s], bA[s], a2, 0, 0, 0);
      }
      int ci = 2 * i * 32 + m;
      #pragma unroll
      for (int j = 0; j < 16; j++) {
        float sc = fmaf(-2.f, a0[j] + a1[j] + a2[j], enA);
        if (sc < bsc[j]) { bsc[j] = sc; bix[j] = ci; }  // ascending ci: ties -> smaller
      }
    }
    // prefetch tile 2i+2 into bA
    if (i < 15) {
      const unsigned short* p = eb + (2 * i + 2) * 4096;
      #pragma unroll
      for (int s = 0; s < 4; s++) {
        bA[s]     = *(const short8*)(p + 16 * s);
        bA[4 + s] = *(const short8*)(p + 64 + 16 * s);
      }
      enA = enorm[(2 * i + 2) * 32 + m];
    }
    // compute tile tB from bB
    {
      float16v a0 = {}, a1 = {}, a2 = {};
      #pragma unroll
      for (int s = 0; s < 4; s++) {
        a0 = __builtin_amdgcn_mfma_f32_32x32x16_bf16(afr[s], bB[s], a0, 0, 0, 0);
        a1 = __builtin_amdgcn_mfma_f32_32x32x16_bf16(afr[s], bB[4 + s], a1, 0, 0, 0);
        a2 = __builtin_amdgcn_mfma_f32_32x32x16_bf16(afr[4 + s], bB[s], a2, 0, 0, 0);
      }
      int ci = tB * 32 + m;
      #pragma unroll
      for (int j = 0; j < 16; j++) {
        float sc = fmaf(-2.f, a0[j] + a1[j] + a2[j], enB);
        if (sc < bsc[j]) { bsc[j] = sc; bix[j] = ci; }
      }
    }
  }

  // C layout: row = (j&3)+8*(j>>2)+4*half, col = m. Reduce each j over the
  // 32 cols (xor masks 1..16 stay within the half), lane m==0 writes.
  #pragma unroll
  for (int j = 0; j < 16; j++) {
    unsigned long long key =
        ((unsigned long long)orderf(bsc[j]) << 32) | (unsigned int)bix[j];
    #pragma unroll
    for (int mm = 1; mm < 32; mm <<= 1) {
      unsigned long long o = shfl_xor_u64(key, mm);
      if (o < key) key = o;
    }
    if (m == 0) {
      int row_local = (j & 3) + 8 * (j >> 2) + 4 * half;
      int grow = row_base + row_local;
      int cidx = (int)(key & 0xffffffffull);
      idx_ws[grow] = cidx;
      outidx[grow] = (float)cidx;
    }
  }
}

// ---------------------------------------------------------------------------
// out + KL: quantized output write + KL partial sums.
// ---------------------------------------------------------------------------
__launch_bounds__(256)
__global__ void out_kl_kernel(const float* __restrict__ inp,
                              const float* __restrict__ Ew,
                              const float* __restrict__ SE,
                              const int* __restrict__ idx_ws,
                              float* __restrict__ out,
                              float* __restrict__ klacc) {
  int row = blockIdx.x * 256 + threadIdx.x;
  int b = row >> 12, l = row & 4095;
  const float* xp = inp + (size_t)b * DDIM * LDIM + l;
  float* op = out + (size_t)b * DDIM * LDIM + l;
  int k = idx_ws[row];
  const float* Ek = Ew + k * DDIM;
  const float* Qk = SE + k * DDIM;

  float Z = 0.f, S1 = 0.f, U = 0.f;
  #pragma unroll
  for (int d = 0; d < 64; d++) {
    float x = xp[d * LDIM];
    float e = expf(x);
    Z += e;
    S1 += e * x;
    U += e * Qk[d];
    op[d * LDIM] = Ek[d];
  }

  float kl = (S1 - U) / Z - logf(Z);
  #pragma unroll
  for (int o = 32; o > 0; o >>= 1) kl += __shfl_xor(kl, o, 64);
  if ((threadIdx.x & 63) == 0) atomicAdd(klacc, kl);
}

// ---------------------------------------------------------------------------
// dw partial: dimension-sliced histogram; d==0 blocks also histogram counts.
// Zero global atomics.
// ---------------------------------------------------------------------------
__launch_bounds__(256)
__global__ void dw_partial_kernel(const float* __restrict__ inp,
                                  const int* __restrict__ idx_ws,
                                  float* __restrict__ partial,
                                  float* __restrict__ pcounts) {
  __shared__ float dwp[KCODES];
  __shared__ float cnt[KCODES];
  const int d = blockIdx.x & 63;
  const int slice = blockIdx.x >> 6;
  const int tid = threadIdx.x;
  const bool do_cnt = (d == 0);

  #pragma unroll
  for (int i = 0; i < KCODES / 256; i++) {
    dwp[tid + i * 256] = 0.f;
    cnt[tid + i * 256] = 0.f;
  }
  __syncthreads();

  const int r0 = slice * SLICE_ROWS;
  for (int i = tid; i < SLICE_ROWS; i += 256) {
    int r = r0 + i;
    int b = r >> 12, l = r & 4095;
    float x = inp[(size_t)b * DDIM * LDIM + (size_t)d * LDIM + l];
    int k = idx_ws[r];
    atomicAdd(&dwp[k], x);
    if (do_cnt) atomicAdd(&cnt[k], 1.0f);
  }
  __syncthreads();

  float* dst = partial + ((size_t)slice * 64 + d) * KCODES;
  #pragma unroll
  for (int i = 0; i < KCODES / 256; i++) dst[tid + i * 256] = dwp[tid + i * 256];
  if (do_cnt) {
    float* cd = pcounts + (size_t)slice * KCODES;
    #pragma unroll
    for (int i = 0; i < KCODES / 256; i++) cd[tid + i * 256] = cnt[tid + i * 256];
  }
}

// ---------------------------------------------------------------------------
// csp + perplexity (from count partials). 1 block x 1024.
// ---------------------------------------------------------------------------
__global__ void csp_kernel(const float* __restrict__ ema_cs,
                           const float* __restrict__ pcounts,
                           float* __restrict__ csp,
                           float* __restrict__ perp_out) {
  __shared__ float red1[16], red2[16];
  int k = threadIdx.x;
  float c = 0.f;
  #pragma unroll
  for (int sl = 0; sl < NSLICE; sl++) c += pcounts[sl * KCODES + k];
  float cs = ema_cs[k] * 0.9f + 0.1f * c;
  float n = cs;
  #pragma unroll
  for (int o = 32; o > 0; o >>= 1) n += __shfl_xor(n, o, 64);
  if ((k & 63) == 0) red1[k >> 6] = n;
  float a = c * (1.0f / 65536.0f);
  float ent = a * logf(a + 1e-10f);
  float es = ent;
  #pragma unroll
  for (int o = 32; o > 0; o >>= 1) es += __shfl_xor(es, o, 64);
  if ((k & 63) == 0) red2[k >> 6] = es;
  __syncthreads();
  if (k == 0) {
    float t1 = 0.f, t2 = 0.f;
    for (int i = 0; i < 16; i++) { t1 += red1[i]; t2 += red2[i]; }
    red1[0] = t1;
    *perp_out = expf(-t2);
  }
  __syncthreads();
  float N = red1[0];
  csp[k] = (cs + 1e-5f) / (N + 1024.0f * 1e-5f) * N;
}

// ---------------------------------------------------------------------------
// reduce partials + embed epilogue + loss scalar.
// ---------------------------------------------------------------------------
__launch_bounds__(256)
__global__ void reduce_embed_kernel(const float* __restrict__ partial,
                                    const float* __restrict__ emaw,
                                    const float* __restrict__ csp,
                                    const float* __restrict__ klacc,
                                    float* __restrict__ emb_out,
                                    float* __restrict__ loss_out) {
  int i = blockIdx.x * 256 + threadIdx.x;
  int k = i >> 6, d = i & 63;
  float s = 0.f;
  #pragma unroll
  for (int sl = 0; sl < NSLICE; sl++)
    s += partial[((size_t)sl * 64 + d) * KCODES + k];
  float v = fmaf(0.1f, s, emaw[i] * 0.9f);
  emb_out[i] = v / csp[k];
  if (i == 0) *loss_out = 0.1f * (*klacc) * (1.0f / 16.0f);
}

extern "C" void kernel_launch(void* const* d_in, const int* in_sizes, int n_in,
                              void* d_out, int out_size, void* d_ws, size_t ws_size,
                              hipStream_t stream) {
  const float* inp   = (const float*)d_in[0];   // (16,64,4096)
  const float* Ew    = (const float*)d_in[1];   // (1024,64)
  const float* emacs = (const float*)d_in[2];   // (1024,)
  const float* emaw  = (const float*)d_in[3];   // (1024,64)

  float* out      = (float*)d_out;              // (16,64,4096) = 4194304
  float* loss_out = out + 4194304;
  float* perp_out = out + 4194305;
  float* emb_out  = out + 4194306;              // 65536
  float* idxf_out = out + 4194306 + 65536;      // 65536 (indices as float)

  char* ws = (char*)d_ws;
  int*   idx_ws  = (int*)(ws);                  // 262144 B
  float* klacc   = (float*)(ws + 262144);       // 256 B (zeroed)
  float* enorm   = (float*)(ws + 266496);       // 4096 B
  float* csp     = (float*)(ws + 270592);       // 4096 B
  float* SE      = (float*)(ws + 274688);       // 262144 B -> ends 536832
  unsigned short* Epk = (unsigned short*)(ws + 536832);   // 262144 B
  // dw partials alias Epk (dead after argmin)
  float* partial = (float*)(ws + 536832);       // 2097152 B -> ends 2633984
  float* pcounts = (float*)(ws + 2633984);      // 32768 B  -> ends 2666752

  hipMemsetAsync(ws + 262144, 0, 256, stream);

  prep_kernel<<<KCODES, 64, 0, stream>>>(Ew, enorm, SE, Epk);
  argmin_kernel<<<512, 256, 0, stream>>>(inp, Epk, enorm, idx_ws, idxf_out);
  dw_partial_kernel<<<64 * NSLICE, 256, 0, stream>>>(inp, idx_ws, partial, pcounts);
  csp_kernel<<<1, 1024, 0, stream>>>(emacs, pcounts, csp, perp_out);
  out_kl_kernel<<<NROWS / 256, 256, 0, stream>>>(inp, Ew, SE, idx_ws, out, klacc);
  reduce_embed_kernel<<<NROWS / 256, 256, 0, stream>>>(partial, emaw, csp, klacc,
                                                       emb_out, loss_out);
}

// Round 8
// 179.234 us; speedup vs baseline: 1.6237x; 1.2001x over previous
//
#include <hip/hip_runtime.h>

#define LDIM 4096
#define DDIM 64
#define KCODES 1024
#define BDIM 16
#define NROWS 65536   // BDIM * LDIM
#define NSLICE 8
#define SLICE_ROWS (NROWS / NSLICE)   // 8192

typedef __attribute__((ext_vector_type(8))) short short8;
typedef __attribute__((ext_vector_type(16))) float float16v;

__device__ __forceinline__ unsigned int orderf(float f) {
  unsigned int u = __float_as_uint(f);
  return (u & 0x80000000u) ? ~u : (u | 0x80000000u);
}

__device__ __forceinline__ unsigned long long shfl_xor_u64(unsigned long long v, int m) {
  int lo = __shfl_xor((int)(unsigned int)(v & 0xffffffffull), m, 64);
  int hi = __shfl_xor((int)(unsigned int)(v >> 32), m, 64);
  return ((unsigned long long)(unsigned int)hi << 32) | (unsigned int)lo;
}

// bf16 RNE high part (as ushort bits)
__device__ __forceinline__ unsigned int bf16_rne(float x) {
  unsigned int u = __float_as_uint(x);
  return (u + 0x7FFFu + ((u >> 16) & 1u)) >> 16;
}

// ---------------------------------------------------------------------------
// prep: per-code norm + softmax table + FRAGMENT-LOAD-ORDER bf16 codebook.
// For tile t (32 codes), load-instruction q (0..3 hi s, 4..7 lo s), lane
// (h*32+m): 8 shorts = B-frag of code c=t*32+m, dims d=16s+8h+[0,8).
// Short index: t*4096 + q*512 + (h*32+m)*8 + j. A wave load at
// (t*4096 + q*512 + lane*8) is contiguous 1 KB -> fully coalesced.
// ---------------------------------------------------------------------------
__global__ void prep_kernel(const float* __restrict__ Ew,
                            float* __restrict__ enorm,
                            float* __restrict__ SE,
                            unsigned short* __restrict__ Epk2) {
  int k = blockIdx.x;
  int d = threadIdx.x;
  float v = Ew[k * DDIM + d];
  float n2 = v * v;
  #pragma unroll
  for (int o = 32; o > 0; o >>= 1) n2 += __shfl_xor(n2, o, 64);
  float m = v;
  #pragma unroll
  for (int o = 32; o > 0; o >>= 1) m = fmaxf(m, __shfl_xor(m, o, 64));
  float e = expf(v - m);
  float Z = e;
  #pragma unroll
  for (int o = 32; o > 0; o >>= 1) Z += __shfl_xor(Z, o, 64);
  SE[k * DDIM + d] = e / Z;
  if (d == 0) enorm[k] = n2;

  unsigned int rh = bf16_rne(v);
  float hif = __uint_as_float(rh << 16);
  unsigned int rl = bf16_rne(v - hif);
  int tile = k >> 5, mm = k & 31;
  int s = d >> 4, h = (d >> 3) & 1, j = d & 7;
  int base = tile * 4096 + (h * 32 + mm) * 8 + j;
  Epk2[base + s * 512]        = (unsigned short)rh;
  Epk2[base + (4 + s) * 512]  = (unsigned short)rl;
}

// ---------------------------------------------------------------------------
// argmin: LDS-free, barrier-free, atomic-free. One wave owns 32 rows.
// A-frags (x hi/lo) from coalesced strided global loads; B streamed from the
// fragment-linear codebook -> every load is a contiguous 1 KB wave access
// (sequential through 256 KB, L1/L2-hot). Register double-buffered tiles,
// 3 independent MFMA chains, butterfly argmin, direct writes.
// score = ||E||^2 - 2 x.E  (row-constant ||x||^2 dropped; order/ties kept).
// ---------------------------------------------------------------------------
__launch_bounds__(256, 2)
__global__ void argmin_kernel(const float* __restrict__ inp,
                              const unsigned short* __restrict__ Epk2,
                              const float* __restrict__ enorm,
                              int* __restrict__ idx_ws,
                              float* __restrict__ outidx) {
  const int tid = threadIdx.x;
  const int lane = tid & 63;
  const int w = tid >> 6;
  const int half = lane >> 5;
  const int m = lane & 31;
  const int row_base = blockIdx.x * 128 + w * 32;
  const int b = row_base >> 12;
  const int l0 = row_base & 4095;
  const float* xp = inp + (size_t)b * DDIM * LDIM + l0 + m;

  // ---- A-frags from global: lane holds x[row=m][d=16s+8*half+j] --------
  short8 afr[8];   // 0..3 = hi frags, 4..7 = lo frags
  #pragma unroll
  for (int s = 0; s < 4; s++) {
    #pragma unroll
    for (int j = 0; j < 8; j++) {
      int d = 16 * s + 8 * half + j;
      float x = xp[(size_t)d * LDIM];
      unsigned int rh = bf16_rne(x);
      float hif = __uint_as_float(rh << 16);
      unsigned int rl = bf16_rne(x - hif);
      afr[s][j] = (short)(unsigned short)rh;
      afr[4 + s][j] = (short)(unsigned short)rl;
    }
  }

  float bsc[16];
  int bix[16];
  #pragma unroll
  for (int j = 0; j < 16; j++) { bsc[j] = 1e30f; bix[j] = 0; }

  // per-lane element base: frag q of tile t at eb + t*4096 + q*512
  const unsigned short* eb = Epk2 + lane * 8;

  short8 bA[8], bB[8];
  float enA, enB;

  // load tile 0
  #pragma unroll
  for (int s = 0; s < 4; s++) {
    bA[s]     = *(const short8*)(eb + s * 512);
    bA[4 + s] = *(const short8*)(eb + 2048 + s * 512);
  }
  enA = enorm[m];

  #pragma unroll 1
  for (int i = 0; i < 16; i++) {
    const int tB = 2 * i + 1;
    // prefetch tile tB (coalesced 1 KB per load)
    {
      const unsigned short* p = eb + tB * 4096;
      #pragma unroll
      for (int s = 0; s < 4; s++) {
        bB[s]     = *(const short8*)(p + s * 512);
        bB[4 + s] = *(const short8*)(p + 2048 + s * 512);
      }
      enB = enorm[tB * 32 + m];
    }
    // compute tile 2i from bA
    {
      float16v a0 = {}, a1 = {}, a2 = {};
      #pragma unroll
      for (int s = 0; s < 4; s++) {
        a0 = __builtin_amdgcn_mfma_f32_32x32x16_bf16(afr[s], bA[s], a0, 0, 0, 0);
        a1 = __builtin_amdgcn_mfma_f32_32x32x16_bf16(afr[s], bA[4 + s], a1, 0, 0, 0);
        a2 = __builtin_amdgcn_mfma_f32_32x32x16_bf16(afr[4 + s], bA[s], a2, 0, 0, 0);
      }
      int ci = 2 * i * 32 + m;
      #pragma unroll
      for (int j = 0; j < 16; j++) {
        float sc = fmaf(-2.f, a0[j] + a1[j] + a2[j], enA);
        if (sc < bsc[j]) { bsc[j] = sc; bix[j] = ci; }  // ascending ci: ties -> smaller
      }
    }
    // prefetch tile 2i+2 into bA
    if (i < 15) {
      const unsigned short* p = eb + (2 * i + 2) * 4096;
      #pragma unroll
      for (int s = 0; s < 4; s++) {
        bA[s]     = *(const short8*)(p + s * 512);
        bA[4 + s] = *(const short8*)(p + 2048 + s * 512);
      }
      enA = enorm[(2 * i + 2) * 32 + m];
    }
    // compute tile tB from bB
    {
      float16v a0 = {}, a1 = {}, a2 = {};
      #pragma unroll
      for (int s = 0; s < 4; s++) {
        a0 = __builtin_amdgcn_mfma_f32_32x32x16_bf16(afr[s], bB[s], a0, 0, 0, 0);
        a1 = __builtin_amdgcn_mfma_f32_32x32x16_bf16(afr[s], bB[4 + s], a1, 0, 0, 0);
        a2 = __builtin_amdgcn_mfma_f32_32x32x16_bf16(afr[4 + s], bB[s], a2, 0, 0, 0);
      }
      int ci = tB * 32 + m;
      #pragma unroll
      for (int j = 0; j < 16; j++) {
        float sc = fmaf(-2.f, a0[j] + a1[j] + a2[j], enB);
        if (sc < bsc[j]) { bsc[j] = sc; bix[j] = ci; }
      }
    }
  }

  // C layout: row = (j&3)+8*(j>>2)+4*half, col = m. Butterfly min over cols.
  #pragma unroll
  for (int j = 0; j < 16; j++) {
    unsigned long long key =
        ((unsigned long long)orderf(bsc[j]) << 32) | (unsigned int)bix[j];
    #pragma unroll
    for (int mm = 1; mm < 32; mm <<= 1) {
      unsigned long long o = shfl_xor_u64(key, mm);
      if (o < key) key = o;
    }
    if (m == 0) {
      int row_local = (j & 3) + 8 * (j >> 2) + 4 * half;
      int grow = row_base + row_local;
      int cidx = (int)(key & 0xffffffffull);
      idx_ws[grow] = cidx;
      outidx[grow] = (float)cidx;
    }
  }
}

// ---------------------------------------------------------------------------
// out + KL: 1024 blocks; block = 64 rows x 4 d-chunks of 16 (chunk = wave).
// Coalesced x/out access per d; float4 gathers for Ek/Qk; LDS partial
// combine; one kl atomic per 64 rows.
// ---------------------------------------------------------------------------
__launch_bounds__(256)
__global__ void out_kl_kernel(const float* __restrict__ inp,
                              const float* __restrict__ Ew,
                              const float* __restrict__ SE,
                              const int* __restrict__ idx_ws,
                              float* __restrict__ out,
                              float* __restrict__ klacc) {
  __shared__ float Zs[4][64], S1s[4][64], Us[4][64];
  const int tid = threadIdx.x;
  const int c = tid >> 6;       // d-chunk (= wave)
  const int i = tid & 63;       // row within block
  const int r = blockIdx.x * 64 + i;
  const int b = r >> 12, l = r & 4095;
  const float* xp = inp + (size_t)b * DDIM * LDIM + l;
  float* op = out + (size_t)b * DDIM * LDIM + l;
  const int k = idx_ws[r];
  const float4* Ek4 = (const float4*)(Ew + k * DDIM) + c * 4;
  const float4* Qk4 = (const float4*)(SE + k * DDIM) + c * 4;

  float Z = 0.f, S1 = 0.f, U = 0.f;
  #pragma unroll
  for (int t = 0; t < 4; t++) {
    float ek[4], qk[4];
    *(float4*)ek = Ek4[t];
    *(float4*)qk = Qk4[t];
    #pragma unroll
    for (int u = 0; u < 4; u++) {
      int d = c * 16 + t * 4 + u;
      float x = xp[(size_t)d * LDIM];
      float e = expf(x);
      Z += e;
      S1 += e * x;
      U += e * qk[u];
      op[(size_t)d * LDIM] = ek[u];
    }
  }
  Zs[c][i] = Z; S1s[c][i] = S1; Us[c][i] = U;
  __syncthreads();
  if (tid < 64) {
    float Zt = Zs[0][i] + Zs[1][i] + Zs[2][i] + Zs[3][i];
    float S1t = S1s[0][i] + S1s[1][i] + S1s[2][i] + S1s[3][i];
    float Ut = Us[0][i] + Us[1][i] + Us[2][i] + Us[3][i];
    float kl = (S1t - Ut) / Zt - logf(Zt);
    #pragma unroll
    for (int o = 32; o > 0; o >>= 1) kl += __shfl_xor(kl, o, 64);
    if (i == 0) atomicAdd(klacc, kl);
  }
}

// ---------------------------------------------------------------------------
// dw partial: dimension-sliced histogram, 512 thr/block (16 waves/CU);
// d==0 blocks also histogram counts. Zero global atomics.
// ---------------------------------------------------------------------------
__launch_bounds__(512)
__global__ void dw_partial_kernel(const float* __restrict__ inp,
                                  const int* __restrict__ idx_ws,
                                  float* __restrict__ partial,
                                  float* __restrict__ pcounts) {
  __shared__ float dwp[KCODES];
  __shared__ float cnt[KCODES];
  const int d = blockIdx.x & 63;
  const int slice = blockIdx.x >> 6;
  const int tid = threadIdx.x;
  const bool do_cnt = (d == 0);

  #pragma unroll
  for (int i = 0; i < KCODES / 512; i++) {
    dwp[tid + i * 512] = 0.f;
    cnt[tid + i * 512] = 0.f;
  }
  __syncthreads();

  const int r0 = slice * SLICE_ROWS;
  for (int i = tid; i < SLICE_ROWS; i += 512) {
    int r = r0 + i;
    int b = r >> 12, l = r & 4095;
    float x = inp[(size_t)b * DDIM * LDIM + (size_t)d * LDIM + l];
    int k = idx_ws[r];
    atomicAdd(&dwp[k], x);
    if (do_cnt) atomicAdd(&cnt[k], 1.0f);
  }
  __syncthreads();

  float* dst = partial + ((size_t)slice * 64 + d) * KCODES;
  #pragma unroll
  for (int i = 0; i < KCODES / 512; i++) dst[tid + i * 512] = dwp[tid + i * 512];
  if (do_cnt) {
    float* cd = pcounts + (size_t)slice * KCODES;
    #pragma unroll
    for (int i = 0; i < KCODES / 512; i++) cd[tid + i * 512] = cnt[tid + i * 512];
  }
}

// ---------------------------------------------------------------------------
// csp + perplexity (from count partials). 1 block x 1024.
// ---------------------------------------------------------------------------
__global__ void csp_kernel(const float* __restrict__ ema_cs,
                           const float* __restrict__ pcounts,
                           float* __restrict__ csp,
                           float* __restrict__ perp_out) {
  __shared__ float red1[16], red2[16];
  int k = threadIdx.x;
  float c = 0.f;
  #pragma unroll
  for (int sl = 0; sl < NSLICE; sl++) c += pcounts[sl * KCODES + k];
  float cs = ema_cs[k] * 0.9f + 0.1f * c;
  float n = cs;
  #pragma unroll
  for (int o = 32; o > 0; o >>= 1) n += __shfl_xor(n, o, 64);
  if ((k & 63) == 0) red1[k >> 6] = n;
  float a = c * (1.0f / 65536.0f);
  float ent = a * logf(a + 1e-10f);
  float es = ent;
  #pragma unroll
  for (int o = 32; o > 0; o >>= 1) es += __shfl_xor(es, o, 64);
  if ((k & 63) == 0) red2[k >> 6] = es;
  __syncthreads();
  if (k == 0) {
    float t1 = 0.f, t2 = 0.f;
    for (int i = 0; i < 16; i++) { t1 += red1[i]; t2 += red2[i]; }
    red1[0] = t1;
    *perp_out = expf(-t2);
  }
  __syncthreads();
  float N = red1[0];
  csp[k] = (cs + 1e-5f) / (N + 1024.0f * 1e-5f) * N;
}

// ---------------------------------------------------------------------------
// reduce partials + embed epilogue + loss scalar.
// ---------------------------------------------------------------------------
__launch_bounds__(256)
__global__ void reduce_embed_kernel(const float* __restrict__ partial,
                                    const float* __restrict__ emaw,
                                    const float* __restrict__ csp,
                                    const float* __restrict__ klacc,
                                    float* __restrict__ emb_out,
                                    float* __restrict__ loss_out) {
  int i = blockIdx.x * 256 + threadIdx.x;
  int k = i >> 6, d = i & 63;
  float s = 0.f;
  #pragma unroll
  for (int sl = 0; sl < NSLICE; sl++)
    s += partial[((size_t)sl * 64 + d) * KCODES + k];
  float v = fmaf(0.1f, s, emaw[i] * 0.9f);
  emb_out[i] = v / csp[k];
  if (i == 0) *loss_out = 0.1f * (*klacc) * (1.0f / 16.0f);
}

extern "C" void kernel_launch(void* const* d_in, const int* in_sizes, int n_in,
                              void* d_out, int out_size, void* d_ws, size_t ws_size,
                              hipStream_t stream) {
  const float* inp   = (const float*)d_in[0];   // (16,64,4096)
  const float* Ew    = (const float*)d_in[1];   // (1024,64)
  const float* emacs = (const float*)d_in[2];   // (1024,)
  const float* emaw  = (const float*)d_in[3];   // (1024,64)

  float* out      = (float*)d_out;              // (16,64,4096) = 4194304
  float* loss_out = out + 4194304;
  float* perp_out = out + 4194305;
  float* emb_out  = out + 4194306;              // 65536
  float* idxf_out = out + 4194306 + 65536;      // 65536 (indices as float)

  char* ws = (char*)d_ws;
  int*   idx_ws  = (int*)(ws);                  // 262144 B
  float* klacc   = (float*)(ws + 262144);       // 256 B (zeroed)
  float* enorm   = (float*)(ws + 266496);       // 4096 B
  float* csp     = (float*)(ws + 270592);       // 4096 B
  float* SE      = (float*)(ws + 274688);       // 262144 B -> ends 536832
  unsigned short* Epk2 = (unsigned short*)(ws + 536832);  // 262144 B
  // dw partials alias Epk2 (dead after argmin)
  float* partial = (float*)(ws + 536832);       // 2097152 B -> ends 2633984
  float* pcounts = (float*)(ws + 2633984);      // 32768 B  -> ends 2666752

  hipMemsetAsync(ws + 262144, 0, 256, stream);

  prep_kernel<<<KCODES, 64, 0, stream>>>(Ew, enorm, SE, Epk2);
  argmin_kernel<<<512, 256, 0, stream>>>(inp, Epk2, enorm, idx_ws, idxf_out);
  dw_partial_kernel<<<64 * NSLICE, 512, 0, stream>>>(inp, idx_ws, partial, pcounts);
  csp_kernel<<<1, 1024, 0, stream>>>(emacs, pcounts, csp, perp_out);
  out_kl_kernel<<<NROWS / 64, 256, 0, stream>>>(inp, Ew, SE, idx_ws, out, klacc);
  reduce_embed_kernel<<<NROWS / 256, 256, 0, stream>>>(partial, emaw, csp, klacc,
                                                       emb_out, loss_out);
}